// Round 2
// baseline (133.331 us; speedup 1.0000x reference)
//
#include <hip/hip_runtime.h>

// Pendulum2 constrained-dynamics DAE forward, closed-form per row.
// m = [1, 50], l = [1, 1], g = 10  ->  minv = [1,1,0.02,0.02].
//
// Memory-bound streaming kernel: 64 MiB in + 64 MiB out; roofline ~21 us at
// the 6.5 TB/s the harness's own fillBuffer achieves on this chip.
//
// Structure: ONE THREAD PER ROW (2 float4s = 32 B in, 32 B out).
//   - two dwordx4 loads at addresses 32r and 32r+16: a wave's two load
//     instructions exactly tile the contiguous 2 KiB segment -> every 128 B
//     cache line fully consumed, no shuffle needed to assemble the row.
//   - no ds_swizzle/__shfl in the dependent chain (round-0 used 4 per
//     float4), no parity-divergent select: every thread computes the 2x2
//     constraint solve once and writes both halves of its output row.
//   - non-temporal loads AND stores: pure streaming data, keep it out of
//     L2/L3 (the harness re-poison fills sweep those caches anyway).
//   - full grid (8192 blocks x 256), ~4x wave oversubscription -- round-1's
//     2048-block/unroll-8 variant (exactly 1x machine fill) regressed ~9 us,
//     so oversubscription is doing the latency hiding here.
//
// Math (verified against the JAX reference, absmax-pass in rounds 0-1):
//   phi_q  = [[2x0,2y0,0,0],[2dx,2dy,-2dx,-2dy]],  d=(x0-x1, y0-y1)
//   L = phi_q Minv phi_q^T = [[4|p0|^2, 4(p0.d)],[4(p0.d), 4.08|d|^2]]
//   R1 = -20 y0 + 2|v0|^2 ;  R2 = 2|dv|^2   (gravity cancels in R2)
//   a  = Minv (F - phi_q^T lam)

typedef float vfloat4_t __attribute__((ext_vector_type(4)));

__global__ __launch_bounds__(256) void pend2_dae_kernel(
    const vfloat4_t* __restrict__ in,   // coords as float4s: [2*n_rows]
    vfloat4_t* __restrict__ out,        // same layout
    int nrows)
{
    int r = blockIdx.x * blockDim.x + threadIdx.x;
    if (r >= nrows) return;

    vfloat4_t p = __builtin_nontemporal_load(&in[2 * r]);      // x0 y0 x1 y1
    vfloat4_t q = __builtin_nontemporal_load(&in[2 * r + 1]);  // u0 w0 u1 w1

    float x0 = p.x, y0 = p.y, x1 = p.z, y1 = p.w;
    float u0 = q.x, w0 = q.y, u1 = q.z, w1 = q.w;

    float dx = x0 - x1, dy = y0 - y1;
    float du = u0 - u1, dw = w0 - w1;

    float L11 = 4.0f * (x0 * x0 + y0 * y0);
    float L12 = 4.0f * (x0 * dx + y0 * dy);
    float L22 = 4.08f * (dx * dx + dy * dy);   // 4 * (1 + 1/50) * |d|^2

    float R1 = -20.0f * y0 + 2.0f * (u0 * u0 + w0 * w0);
    float R2 = 2.0f * (du * du + dw * dw);     // gravity terms cancel exactly

    float det = L11 * L22 - L12 * L12;
    float inv = 1.0f / det;
    float lam1 = (L22 * R1 - L12 * R2) * inv;
    float lam2 = (L11 * R2 - L12 * R1) * inv;

    vfloat4_t a;
    a.x = -2.0f * (x0 * lam1 + dx * lam2);
    a.y = -10.0f - 2.0f * (y0 * lam1 + dy * lam2);
    a.z = 0.04f * dx * lam2;
    a.w = -10.0f + 0.04f * dy * lam2;

    __builtin_nontemporal_store(q, &out[2 * r]);      // velocity passthrough
    __builtin_nontemporal_store(a, &out[2 * r + 1]);  // accelerations
}

extern "C" void kernel_launch(void* const* d_in, const int* in_sizes, int n_in,
                              void* d_out, int out_size, void* d_ws, size_t ws_size,
                              hipStream_t stream) {
    // d_in[0] = t (unused, autonomous system), d_in[1] = coords [bs, 8] fp32
    const vfloat4_t* coords = (const vfloat4_t*)d_in[1];
    vfloat4_t* out = (vfloat4_t*)d_out;
    int nrows = in_sizes[1] / 8;   // rows of 8 floats

    int block = 256;
    int grid = (nrows + block - 1) / block;
    pend2_dae_kernel<<<grid, block, 0, stream>>>(coords, out, nrows);
}

// Round 3
// 109.024 us; speedup vs baseline: 1.2230x; 1.2230x over previous
//
#include <hip/hip_runtime.h>

// Pendulum2 constrained-dynamics DAE forward, closed-form per row.
// m = [1, 50], l = [1, 1], g = 10  ->  minv = [1,1,0.02,0.02].
//
// Memory-bound streaming kernel: 64 MiB in + 64 MiB out; ideal ~21 us at the
// 6.45 TB/s the harness's own fillBuffer achieves. Measured floor in dur_us
// includes ~83+ us of harness re-poison fills; kernel-only budget ~26 us (r0).
//
// Structure == round-0 verified best (109.7 us), ONE CHANGE: the lane^1
// exchange uses DPP quad_perm(1,0,3,2) instead of __shfl_xor.
//   - __shfl_xor lowers to ds_bpermute/ds_swizzle: LDS pipe, ~120 cy lgkm
//     latency in EVERY thread's dependent chain (load -> exchange -> compute
//     -> store).
//   - DPP mov with quad_perm is a VALU-pipe register move (~1 cy), no lgkm
//     wait, no LDS traffic. Lane^1 stays inside a quad, so quad_perm is
//     exactly the xor-1 exchange.
//   - loads: plain cached dwordx4, unit stride (16 B/lane, lines fully
//     consumed by one instruction). NT loads were a ~14 us regression in r2
//     (bypass L1/L2 -> refetch overlap lines). NT is kept on stores only
//     (pure streaming output, never re-read).
//   - full grid (16384 blocks x 256), 1 float4/thread: r1 showed the capped
//     2048-block grid-stride shape loses ~9 us -- oversubscription is doing
//     the latency hiding here.

typedef float vfloat4_t __attribute__((ext_vector_type(4)));

// Lane^1 exchange via DPP quad_perm [1,0,3,2] (ctrl 0xB1). All lanes of a
// pair are always both active: n4 is even and pairs share a quad.
__device__ __forceinline__ float dpp_swap1(float x) {
    int i = __builtin_bit_cast(int, x);
    i = __builtin_amdgcn_mov_dpp(i, 0xB1, 0xF, 0xF, true);
    return __builtin_bit_cast(float, i);
}

__global__ __launch_bounds__(256) void pend2_dae_kernel(
    const float4* __restrict__ in,   // coords as float4s: [2*n_rows]
    float4* __restrict__ out,        // same layout
    int n4)                          // number of float4s = 2*n_rows
{
    int j = blockIdx.x * blockDim.x + threadIdx.x;
    if (j >= n4) return;

    float4 mine = in[j];

    // Exchange with lane partner (pairs are lanes (2k, 2k+1); blockDim is
    // even so float4-index parity == lane parity).
    float4 other;
    other.x = dpp_swap1(mine.x);
    other.y = dpp_swap1(mine.y);
    other.z = dpp_swap1(mine.z);
    other.w = dpp_swap1(mine.w);

    bool odd = (j & 1);
    float4 p = odd ? other : mine;   // x0, y0, x1, y1 (even float4 of the row)
    float4 q = odd ? mine : other;   // u0, w0, u1, w1 (odd  float4 of the row)

    float x0 = p.x, y0 = p.y, x1 = p.z, y1 = p.w;
    float u0 = q.x, w0 = q.y, u1 = q.z, w1 = q.w;

    float dx = x0 - x1, dy = y0 - y1;
    float du = u0 - u1, dw = w0 - w1;

    float L11 = 4.0f * (x0 * x0 + y0 * y0);
    float L12 = 4.0f * (x0 * dx + y0 * dy);
    float L22 = 4.08f * (dx * dx + dy * dy);   // 4 * (1 + 1/50) * |d|^2

    float R1 = -20.0f * y0 + 2.0f * (u0 * u0 + w0 * w0);
    float R2 = 2.0f * (du * du + dw * dw);     // gravity terms cancel exactly

    float det = L11 * L22 - L12 * L12;
    float inv = 1.0f / det;
    float lam1 = (L22 * R1 - L12 * R2) * inv;
    float lam2 = (L11 * R2 - L12 * R1) * inv;

    vfloat4_t res;
    if (odd) {
        res.x = -2.0f * (x0 * lam1 + dx * lam2);
        res.y = -10.0f - 2.0f * (y0 * lam1 + dy * lam2);
        res.z = 0.04f * dx * lam2;
        res.w = -10.0f + 0.04f * dy * lam2;
    } else {
        res.x = q.x; res.y = q.y; res.z = q.z; res.w = q.w;
    }

    __builtin_nontemporal_store(res, (vfloat4_t*)&out[j]);
}

extern "C" void kernel_launch(void* const* d_in, const int* in_sizes, int n_in,
                              void* d_out, int out_size, void* d_ws, size_t ws_size,
                              hipStream_t stream) {
    // d_in[0] = t (unused, autonomous system), d_in[1] = coords [bs, 8] fp32
    const float4* coords = (const float4*)d_in[1];
    float4* out = (float4*)d_out;
    int n4 = in_sizes[1] / 4;   // total float4s (= 2 * batch rows)

    int block = 256;
    int grid = (n4 + block - 1) / block;
    pend2_dae_kernel<<<grid, block, 0, stream>>>(coords, out, n4);
}